// Round 1
// baseline (279.265 us; speedup 1.0000x reference)
//
#include <hip/hip_runtime.h>
#include <hip/hip_bf16.h>

#define NB 8
#define CIN 512
#define COUT 512
#define SDIM 512

typedef __attribute__((ext_vector_type(8))) short short8;
typedef __attribute__((ext_vector_type(4))) float f32x4;

static constexpr float CONV_SCALE = 0.014731391274719740f;  // 1/sqrt(512*9)
static constexpr float LIN_SCALE  = 0.044194173824159216f;  // 1/sqrt(512)

// ---- workspace layout (bytes) ----
static constexpr size_t OFF_S     = 0;                      // 8*512*4      = 16384
static constexpr size_t OFF_WSQ   = 16384;                  // 512*512*4    = 1048576
static constexpr size_t OFF_DEMOD = 1064960;                // 8*512*4      = 16384
static constexpr size_t OFF_XP    = 1081344;                // 8*34*34*512*2= 9469952
static constexpr size_t OFF_WP    = 10551296;               // 4608*512*2   = 4718592
static constexpr size_t OFF_Y1    = 15269888;               // 69222400
static constexpr size_t XP_BYTES  = 9469952;

__device__ __forceinline__ int wpoff(int ps) {  // element (short) offsets
  return ps == 0 ? 0 : ps == 1 ? 1048576 : ps == 2 ? 1572864 : 2097152;
}
__device__ __forceinline__ int y1off(int ps) {  // element (float) offsets
  return ps == 0 ? 0 : ps == 1 ? 4460544 : ps == 2 ? 8785920 : 13111296;
}

__device__ __forceinline__ short f2bf(float f) {
  unsigned u = __builtin_bit_cast(unsigned, f);
  unsigned r = (u + 0x7fffu + ((u >> 16) & 1u)) >> 16;
  return (short)r;
}

__device__ __forceinline__ void load_lds16(const short* g, short* l) {
  __builtin_amdgcn_global_load_lds(
      (const __attribute__((address_space(1))) unsigned int*)g,
      (__attribute__((address_space(3))) unsigned int*)l, 16, 0, 0);
}

// ---- K1: s[b][ci] = lin_scale * <style[b], mod_w[ci]> + mod_b[ci] ----
__global__ void k_style(const float* __restrict__ style, const float* __restrict__ mod_w,
                        const float* __restrict__ mod_b, float* __restrict__ s_out) {
  int wid = threadIdx.x >> 6, lane = threadIdx.x & 63;
  int ci = blockIdx.x * 4 + wid;
  float acc[NB] = {};
  for (int k = lane; k < SDIM; k += 64) {
    float wm = mod_w[ci * SDIM + k];
#pragma unroll
    for (int b = 0; b < NB; ++b) acc[b] += wm * style[b * SDIM + k];
  }
#pragma unroll
  for (int b = 0; b < NB; ++b) {
    float v = acc[b];
    for (int o = 32; o > 0; o >>= 1) v += __shfl_xor(v, o);
    if (lane == 0) s_out[b * CIN + ci] = v * LIN_SCALE + mod_b[ci];
  }
}

// ---- K2: phase-split weights (pre-tiled bf16) + wsq ----
__global__ void k_wprep(const float* __restrict__ w, short* __restrict__ wp,
                        float* __restrict__ wsq) {
  int idx = blockIdx.x * blockDim.x + threadIdx.x;  // (co,ci): 262144
  int co = idx >> 9, ci = idx & 511;
  float wv[3][3];
  float sq = 0.f;
#pragma unroll
  for (int i = 0; i < 9; ++i) {
    float v = w[idx * 9 + i];
    wv[i / 3][i % 3] = v;
    sq += v * v;
  }
  wsq[idx] = sq * CONV_SCALE * CONV_SCALE;
#pragma unroll
  for (int wy = 0; wy < 3; ++wy)
#pragma unroll
    for (int wx = 0; wx < 3; ++wx) {
      int psy = (wy == 1) ? 1 : 0, psx = (wx == 1) ? 1 : 0;
      int u = psy ? 0 : (wy == 0 ? 1 : 0);   // wy = 2-2u
      int v = psx ? 0 : (wx == 0 ? 1 : 0);
      int ps = psy * 2 + psx;
      int tap = psy ? (psx ? 0 : v) : (psx ? u : u * 2 + v);
      int k = tap * 512 + ci;
      int elem = wpoff(ps) + ((k >> 6) * 512 + co) * 64 + (k & 63);
      wp[elem] = f2bf(wv[wy][wx] * CONV_SCALE);
    }
}

// ---- K3: demod[b][co] = rsqrt(sum_ci wsq*s^2 + eps) ----
__global__ void k_demod(const float* __restrict__ wsq, const float* __restrict__ s,
                        float* __restrict__ demod) {
  int wid = threadIdx.x >> 6, lane = threadIdx.x & 63;
  int co = blockIdx.x * 4 + wid;
  float acc[NB] = {};
  for (int ci = lane; ci < CIN; ci += 64) {
    float wq = wsq[co * CIN + ci];
#pragma unroll
    for (int b = 0; b < NB; ++b) {
      float sv = s[b * CIN + ci];
      acc[b] += wq * sv * sv;
    }
  }
#pragma unroll
  for (int b = 0; b < NB; ++b) {
    float v = acc[b];
    for (int o = 32; o > 0; o >>= 1) v += __shfl_xor(v, o);
    if (lane == 0) demod[b * COUT + co] = rsqrtf(v + 1e-8f);
  }
}

// ---- K4: xp[b][yy][xx][ci] = bf16(x[b][ci][yy-1][xx-1] * s[b][ci]), channel-last ----
__global__ void k_xprep(const float* __restrict__ x, const float* __restrict__ s,
                        short* __restrict__ xp) {
  __shared__ float t[64][65];
  int sp0 = blockIdx.x * 64, ci0 = blockIdx.y * 64, b = blockIdx.z;
  for (int r = threadIdx.y; r < 64; r += 4)
    t[r][threadIdx.x] = x[(b * CIN + ci0 + r) * 1024 + sp0 + threadIdx.x];
  __syncthreads();
  int ci = ci0 + threadIdx.x;
  float sv = s[b * CIN + ci];
  for (int r = threadIdx.y; r < 64; r += 4) {
    int sp = sp0 + r;
    int yy = sp >> 5, xx = sp & 31;
    xp[((b * 34 + yy + 1) * 34 + (xx + 1)) * 512 + ci] = f2bf(t[threadIdx.x][r] * sv);
  }
}

// ---- K5: phase GEMMs, y1_ps[co][n] fp32 ----
__global__ __launch_bounds__(256, 2) void k_gemm(const short* __restrict__ xp,
                                                 const short* __restrict__ wp,
                                                 float* __restrict__ y1) {
  int ps = blockIdx.z;
  int psy = ps >> 1, psx = ps & 1;
  int Ny = 33 - psy, Nx = 33 - psx;
  int N = NB * Ny * Nx;
  int n0 = blockIdx.x * 128;
  if (n0 >= N) return;
  int m0 = blockIdx.y * 128;
  int KT = (2 - psy) * (2 - psx) * 8;  // K/64
  const short* wpb = wp + wpoff(ps);
  float* y1b = y1 + y1off(ps);

  __shared__ short sW[128 * 64];  // [m][k]
  __shared__ short sX[128 * 64];  // [n][k]

  int tid = threadIdx.x;
  int wid = tid >> 6, lane = tid & 63;

  // decode n for the 4 X-staging issues (constant over kt)
  int bb[4], ay[4], ax[4];
#pragma unroll
  for (int i = 0; i < 4; ++i) {
    int seg = i * 256 + tid;
    int n = n0 + (seg >> 3);
    if (n >= N) n = N - 1;
    int b = n / (Ny * Nx);
    int rem = n - b * (Ny * Nx);
    int a_y = rem / Nx;
    bb[i] = b; ay[i] = a_y; ax[i] = rem - a_y * Nx;
  }
  int kseg8 = (tid & 7) * 8;

  f32x4 acc[4][4] = {};

  for (int kt = 0; kt < KT; ++kt) {
    int tap = kt >> 3, ci0 = (kt & 7) << 6;
    int oy, ox;
    if (ps == 0)      { oy = tap >> 1; ox = tap & 1; }
    else if (ps == 1) { oy = tap;      ox = 1; }
    else if (ps == 2) { oy = 1;        ox = tap; }
    else              { oy = 1;        ox = 1; }
#pragma unroll
    for (int i = 0; i < 4; ++i) {  // W stage: 128 rows x 128B
      int seg = i * 256 + tid;
      const short* g = wpb + (kt * 512 + m0 + (seg >> 3)) * 64 + kseg8;
      load_lds16(g, &sW[(i * 4 + wid) * 512]);
    }
#pragma unroll
    for (int i = 0; i < 4; ++i) {  // X stage: per-lane gather, 16B along ci
      const short* g = xp + ((bb[i] * 34 + ay[i] + oy) * 34 + ax[i] + ox) * 512 + ci0 + kseg8;
      load_lds16(g, &sX[(i * 4 + wid) * 512]);
    }
    asm volatile("s_waitcnt vmcnt(0)" ::: "memory");
    __syncthreads();

    int wm = (wid >> 1) * 64, wn = (wid & 1) * 64;
#pragma unroll
    for (int ks = 0; ks < 2; ++ks) {
      short8 af[4], bf[4];
#pragma unroll
      for (int mf = 0; mf < 4; ++mf)
        af[mf] = *(const short8*)&sW[(wm + mf * 16 + (lane & 15)) * 64 + ks * 32 + (lane >> 4) * 8];
#pragma unroll
      for (int nf = 0; nf < 4; ++nf)
        bf[nf] = *(const short8*)&sX[(wn + nf * 16 + (lane & 15)) * 64 + ks * 32 + (lane >> 4) * 8];
#pragma unroll
      for (int mf = 0; mf < 4; ++mf)
#pragma unroll
        for (int nf = 0; nf < 4; ++nf)
          acc[mf][nf] = __builtin_amdgcn_mfma_f32_16x16x32_bf16(af[mf], bf[nf], acc[mf][nf], 0, 0, 0);
    }
    __syncthreads();
  }

  int wm = (wid >> 1) * 64, wn = (wid & 1) * 64;
#pragma unroll
  for (int mf = 0; mf < 4; ++mf) {
    int m = m0 + wm + mf * 16 + (lane >> 4) * 4;
#pragma unroll
    for (int nf = 0; nf < 4; ++nf) {
      int n = n0 + wn + nf * 16 + (lane & 15);
      if (n < N) {
#pragma unroll
        for (int r = 0; r < 4; ++r) y1b[(m + r) * N + n] = acc[mf][nf][r];
      }
    }
  }
}

// ---- K6: blur(4x4 FIR over parity planes) + demod + bias + leaky*sqrt2 ----
__global__ void k_blur(const float* __restrict__ y1, const float* __restrict__ demod,
                       const float* __restrict__ bias, float* __restrict__ out) {
  int idx = blockIdx.x * 256 + threadIdx.x;
  int q = idx & 63;
  int p = (idx >> 6) & 63;
  int co = (idx >> 12) & 511;
  int b = idx >> 21;
  int my = p >> 1, fy = p & 1;
  int mx = q >> 1, fx = q & 1;

  int psY[4], aY[4], psX[4], aX[4];
  if (fy) { psY[0]=0; aY[0]=my;   psY[1]=1; aY[1]=my; psY[2]=0; aY[2]=my+1; psY[3]=1; aY[3]=my+1; }
  else    { psY[0]=1; aY[0]=my-1; psY[1]=0; aY[1]=my; psY[2]=1; aY[2]=my;   psY[3]=0; aY[3]=my+1; }
  if (fx) { psX[0]=0; aX[0]=mx;   psX[1]=1; aX[1]=mx; psX[2]=0; aX[2]=mx+1; psX[3]=1; aX[3]=mx+1; }
  else    { psX[0]=1; aX[0]=mx-1; psX[1]=0; aX[1]=mx; psX[2]=1; aX[2]=mx;   psX[3]=0; aX[3]=mx+1; }
  const float cc[4] = {0.25f, 0.75f, 0.75f, 0.25f};

  float sum = 0.f;
#pragma unroll
  for (int i = 0; i < 4; ++i) {
    int pv = psY[i], av = aY[i];
    int Nyv = 33 - pv;
    if (av < 0 || av >= Nyv) continue;
#pragma unroll
    for (int j = 0; j < 4; ++j) {
      int ph = psX[j], ah = aX[j];
      int Nxv = 33 - ph;
      if (ah < 0 || ah >= Nxv) continue;
      int ps = pv * 2 + ph;
      int Nv = NB * Nyv * Nxv;
      sum += cc[i] * cc[j] * y1[y1off(ps) + co * Nv + (b * Nyv + av) * Nxv + ah];
    }
  }
  float val = demod[b * COUT + co] * sum + bias[co];
  out[idx] = (val >= 0.f ? val : 0.2f * val) * 1.41421356237309515f;
}

extern "C" void kernel_launch(void* const* d_in, const int* in_sizes, int n_in,
                              void* d_out, int out_size, void* d_ws, size_t ws_size,
                              hipStream_t stream) {
  const float* x      = (const float*)d_in[0];
  const float* style  = (const float*)d_in[1];
  const float* weight = (const float*)d_in[2];
  const float* mod_w  = (const float*)d_in[3];
  const float* mod_b  = (const float*)d_in[4];
  const float* bias   = (const float*)d_in[5];
  float* out = (float*)d_out;
  char* ws = (char*)d_ws;

  float* s     = (float*)(ws + OFF_S);
  float* wsq   = (float*)(ws + OFF_WSQ);
  float* demod = (float*)(ws + OFF_DEMOD);
  short* xp    = (short*)(ws + OFF_XP);
  short* wp    = (short*)(ws + OFF_WP);
  float* y1    = (float*)(ws + OFF_Y1);

  hipMemsetAsync(xp, 0, XP_BYTES, stream);
  k_style<<<128, 256, 0, stream>>>(style, mod_w, mod_b, s);
  k_wprep<<<1024, 256, 0, stream>>>(weight, wp, wsq);
  k_demod<<<128, 256, 0, stream>>>(wsq, s, demod);
  k_xprep<<<dim3(16, 8, 8), dim3(64, 4), 0, stream>>>(x, s, xp);
  k_gemm<<<dim3(69, 4, 4), 256, 0, stream>>>(xp, wp, y1);
  k_blur<<<65536, 256, 0, stream>>>(y1, demod, bias, out);
}

// Round 2
// 142.610 us; speedup vs baseline: 1.9582x; 1.9582x over previous
//
#include <hip/hip_runtime.h>
#include <hip/hip_bf16.h>

#define NB 8
#define CIN 512
#define COUT 512
#define SDIM 512

typedef __attribute__((ext_vector_type(8))) short short8;
typedef __attribute__((ext_vector_type(4))) float f32x4;

static constexpr float CONV_SCALE = 0.014731391274719740f;  // 1/sqrt(512*9)
static constexpr float LIN_SCALE  = 0.044194173824159216f;  // 1/sqrt(512)

// ---- workspace layout (bytes) ----
static constexpr size_t OFF_S     = 0;                      // 8*512*4      = 16384
static constexpr size_t OFF_WSQ   = 16384;                  // 512*512*4    = 1048576
static constexpr size_t OFF_DEMOD = 1064960;                // 8*512*4      = 16384
static constexpr size_t OFF_XP    = 1081344;                // 8*34*34*512*2= 9469952
static constexpr size_t OFF_WP    = 10551296;               // 4608*512*2   = 4718592
static constexpr size_t OFF_Y1    = 15269888;               // 69222400
static constexpr size_t XP_BYTES  = 9469952;

__device__ __forceinline__ int wpoff(int ps) {  // element (short) offsets
  return ps == 0 ? 0 : ps == 1 ? 1048576 : ps == 2 ? 1572864 : 2097152;
}
__device__ __forceinline__ constexpr int y1off(int ps) {  // element (float) offsets
  return ps == 0 ? 0 : ps == 1 ? 4460544 : ps == 2 ? 8785920 : 13111296;
}

__device__ __forceinline__ short f2bf(float f) {
  unsigned u = __builtin_bit_cast(unsigned, f);
  unsigned r = (u + 0x7fffu + ((u >> 16) & 1u)) >> 16;
  return (short)r;
}

__device__ __forceinline__ void load_lds16(const short* g, short* l) {
  __builtin_amdgcn_global_load_lds(
      (const __attribute__((address_space(1))) unsigned int*)g,
      (__attribute__((address_space(3))) unsigned int*)l, 16, 0, 0);
}

// ---- K1: s[b][ci] = lin_scale * <style[b], mod_w[ci]> + mod_b[ci] ----
__global__ void k_style(const float* __restrict__ style, const float* __restrict__ mod_w,
                        const float* __restrict__ mod_b, float* __restrict__ s_out) {
  int wid = threadIdx.x >> 6, lane = threadIdx.x & 63;
  int ci = blockIdx.x * 4 + wid;
  float acc[NB] = {};
  for (int k = lane; k < SDIM; k += 64) {
    float wm = mod_w[ci * SDIM + k];
#pragma unroll
    for (int b = 0; b < NB; ++b) acc[b] += wm * style[b * SDIM + k];
  }
#pragma unroll
  for (int b = 0; b < NB; ++b) {
    float v = acc[b];
    for (int o = 32; o > 0; o >>= 1) v += __shfl_xor(v, o);
    if (lane == 0) s_out[b * CIN + ci] = v * LIN_SCALE + mod_b[ci];
  }
}

// ---- K2: phase-split weights (pre-tiled bf16) + wsq ----
__global__ void k_wprep(const float* __restrict__ w, short* __restrict__ wp,
                        float* __restrict__ wsq) {
  int idx = blockIdx.x * blockDim.x + threadIdx.x;  // (co,ci): 262144
  int co = idx >> 9, ci = idx & 511;
  float wv[3][3];
  float sq = 0.f;
#pragma unroll
  for (int i = 0; i < 9; ++i) {
    float v = w[idx * 9 + i];
    wv[i / 3][i % 3] = v;
    sq += v * v;
  }
  wsq[idx] = sq * CONV_SCALE * CONV_SCALE;
#pragma unroll
  for (int wy = 0; wy < 3; ++wy)
#pragma unroll
    for (int wx = 0; wx < 3; ++wx) {
      int psy = (wy == 1) ? 1 : 0, psx = (wx == 1) ? 1 : 0;
      int u = psy ? 0 : (wy == 0 ? 1 : 0);   // wy = 2-2u
      int v = psx ? 0 : (wx == 0 ? 1 : 0);
      int ps = psy * 2 + psx;
      int tap = psy ? (psx ? 0 : v) : (psx ? u : u * 2 + v);
      int k = tap * 512 + ci;
      int elem = wpoff(ps) + ((k >> 6) * 512 + co) * 64 + (k & 63);
      wp[elem] = f2bf(wv[wy][wx] * CONV_SCALE);
    }
}

// ---- K3: demod[b][co] = rsqrt(sum_ci wsq*s^2 + eps) ----
__global__ void k_demod(const float* __restrict__ wsq, const float* __restrict__ s,
                        float* __restrict__ demod) {
  int wid = threadIdx.x >> 6, lane = threadIdx.x & 63;
  int co = blockIdx.x * 4 + wid;
  float acc[NB] = {};
  for (int ci = lane; ci < CIN; ci += 64) {
    float wq = wsq[co * CIN + ci];
#pragma unroll
    for (int b = 0; b < NB; ++b) {
      float sv = s[b * CIN + ci];
      acc[b] += wq * sv * sv;
    }
  }
#pragma unroll
  for (int b = 0; b < NB; ++b) {
    float v = acc[b];
    for (int o = 32; o > 0; o >>= 1) v += __shfl_xor(v, o);
    if (lane == 0) demod[b * COUT + co] = rsqrtf(v + 1e-8f);
  }
}

// ---- K4: xp[b][yy][xx][ci] = bf16(x[b][ci][yy-1][xx-1] * s[b][ci]), channel-last ----
__global__ void k_xprep(const float* __restrict__ x, const float* __restrict__ s,
                        short* __restrict__ xp) {
  __shared__ float t[64][65];
  int sp0 = blockIdx.x * 64, ci0 = blockIdx.y * 64, b = blockIdx.z;
  for (int r = threadIdx.y; r < 64; r += 4)
    t[r][threadIdx.x] = x[(b * CIN + ci0 + r) * 1024 + sp0 + threadIdx.x];
  __syncthreads();
  int ci = ci0 + threadIdx.x;
  float sv = s[b * CIN + ci];
  for (int r = threadIdx.y; r < 64; r += 4) {
    int sp = sp0 + r;
    int yy = sp >> 5, xx = sp & 31;
    xp[((b * 34 + yy + 1) * 34 + (xx + 1)) * 512 + ci] = f2bf(t[threadIdx.x][r] * sv);
  }
}

// ---- K5: phase GEMMs, y1_ps[co][n] fp32 ----
__global__ __launch_bounds__(256, 2) void k_gemm(const short* __restrict__ xp,
                                                 const short* __restrict__ wp,
                                                 float* __restrict__ y1) {
  int ps = blockIdx.z;
  int psy = ps >> 1, psx = ps & 1;
  int Ny = 33 - psy, Nx = 33 - psx;
  int N = NB * Ny * Nx;
  int n0 = blockIdx.x * 128;
  if (n0 >= N) return;
  int m0 = blockIdx.y * 128;
  int KT = (2 - psy) * (2 - psx) * 8;  // K/64
  const short* wpb = wp + wpoff(ps);
  float* y1b = y1 + y1off(ps);

  __shared__ short sW[128 * 64];  // [m][k]
  __shared__ short sX[128 * 64];  // [n][k]

  int tid = threadIdx.x;
  int wid = tid >> 6, lane = tid & 63;

  // decode n for the 4 X-staging issues (constant over kt)
  int bb[4], ay[4], ax[4];
#pragma unroll
  for (int i = 0; i < 4; ++i) {
    int seg = i * 256 + tid;
    int n = n0 + (seg >> 3);
    if (n >= N) n = N - 1;
    int b = n / (Ny * Nx);
    int rem = n - b * (Ny * Nx);
    int a_y = rem / Nx;
    bb[i] = b; ay[i] = a_y; ax[i] = rem - a_y * Nx;
  }
  int kseg8 = (tid & 7) * 8;

  f32x4 acc[4][4] = {};

  for (int kt = 0; kt < KT; ++kt) {
    int tap = kt >> 3, ci0 = (kt & 7) << 6;
    int oy, ox;
    if (ps == 0)      { oy = tap >> 1; ox = tap & 1; }
    else if (ps == 1) { oy = tap;      ox = 1; }
    else if (ps == 2) { oy = 1;        ox = tap; }
    else              { oy = 1;        ox = 1; }
#pragma unroll
    for (int i = 0; i < 4; ++i) {  // W stage: 128 rows x 128B
      int seg = i * 256 + tid;
      const short* g = wpb + (kt * 512 + m0 + (seg >> 3)) * 64 + kseg8;
      load_lds16(g, &sW[(i * 4 + wid) * 512]);
    }
#pragma unroll
    for (int i = 0; i < 4; ++i) {  // X stage: per-lane gather, 16B along ci
      const short* g = xp + ((bb[i] * 34 + ay[i] + oy) * 34 + ax[i] + ox) * 512 + ci0 + kseg8;
      load_lds16(g, &sX[(i * 4 + wid) * 512]);
    }
    asm volatile("s_waitcnt vmcnt(0)" ::: "memory");
    __syncthreads();

    int wm = (wid >> 1) * 64, wn = (wid & 1) * 64;
#pragma unroll
    for (int ks = 0; ks < 2; ++ks) {
      short8 af[4], bf[4];
#pragma unroll
      for (int mf = 0; mf < 4; ++mf)
        af[mf] = *(const short8*)&sW[(wm + mf * 16 + (lane & 15)) * 64 + ks * 32 + (lane >> 4) * 8];
#pragma unroll
      for (int nf = 0; nf < 4; ++nf)
        bf[nf] = *(const short8*)&sX[(wn + nf * 16 + (lane & 15)) * 64 + ks * 32 + (lane >> 4) * 8];
#pragma unroll
      for (int mf = 0; mf < 4; ++mf)
#pragma unroll
        for (int nf = 0; nf < 4; ++nf)
          acc[mf][nf] = __builtin_amdgcn_mfma_f32_16x16x32_bf16(af[mf], bf[nf], acc[mf][nf], 0, 0, 0);
    }
    __syncthreads();
  }

  int wm = (wid >> 1) * 64, wn = (wid & 1) * 64;
#pragma unroll
  for (int mf = 0; mf < 4; ++mf) {
    int m = m0 + wm + mf * 16 + (lane >> 4) * 4;
#pragma unroll
    for (int nf = 0; nf < 4; ++nf) {
      int n = n0 + wn + nf * 16 + (lane & 15);
      if (n < N) {
#pragma unroll
        for (int r = 0; r < 4; ++r) y1b[(m + r) * N + n] = acc[mf][nf][r];
      }
    }
  }
}

// ---- K6 v2: LDS-tiled separable blur + demod + bias + leaky*sqrt2 ----
// One block per (b,co) plane. Load 4 phase planes into zero-padded LDS
// [4][35][35] (padded coords = actual + 1), horizontal FIR into tmp[2][35][64],
// vertical FIR -> 64x64 outputs.
__global__ __launch_bounds__(256, 4) void k_blur(const float* __restrict__ y1,
                                                 const float* __restrict__ demod,
                                                 const float* __restrict__ bias,
                                                 float* __restrict__ out) {
  __shared__ float sin_[4][35 * 35];
  __shared__ float stmp[2][35][64];
  const int tid = threadIdx.x;
  const int bc = blockIdx.x;          // b*512 + co
  const int co = bc & 511, b = bc >> 9;

  for (int i = tid; i < 4 * 35 * 35; i += 256) ((float*)sin_)[i] = 0.f;
  __syncthreads();

#pragma unroll
  for (int ps = 0; ps < 4; ++ps) {
    const int Nyv = 33 - (ps >> 1), Nxv = 33 - (ps & 1);
    const float* pl = y1 + y1off(ps) + (co * NB + b) * (Nyv * Nxv);
    for (int t = tid; t < Nyv * Nxv; t += 256) {
      int av = t / Nxv, ah = t - av * Nxv;     // const Nxv -> magic mul
      sin_[ps][(av + 1) * 35 + ah + 1] = pl[t];
    }
  }
  __syncthreads();

  const int q = tid & 63;
  const int mx = q >> 1, fx = q & 1;
  int xp0, xi0, xp1, xi1, xp2, xi2, xp3, xi3;
  if (fx) { xp0 = 0; xi0 = mx + 1; xp1 = 1; xi1 = mx + 1; xp2 = 0; xi2 = mx + 2; xp3 = 1; xi3 = mx + 2; }
  else    { xp0 = 1; xi0 = mx;     xp1 = 0; xi1 = mx + 1; xp2 = 1; xi2 = mx + 1; xp3 = 0; xi3 = mx + 2; }

  for (int r = tid >> 6; r < 70; r += 4) {     // r = pv*35 + padded row
    int pv = (r >= 35) ? 1 : 0;
    int av = r - pv * 35;
    float v = 0.25f * sin_[pv * 2 + xp0][av * 35 + xi0]
            + 0.75f * sin_[pv * 2 + xp1][av * 35 + xi1]
            + 0.75f * sin_[pv * 2 + xp2][av * 35 + xi2]
            + 0.25f * sin_[pv * 2 + xp3][av * 35 + xi3];
    stmp[pv][av][q] = v;
  }
  __syncthreads();

  const float dm = demod[b * COUT + co], bs = bias[co];
  for (int p = tid >> 6; p < 64; p += 4) {
    int my = p >> 1, fy = p & 1;
    float v;
    if (fy) v = 0.25f * stmp[0][my + 1][q] + 0.75f * stmp[1][my + 1][q]
              + 0.75f * stmp[0][my + 2][q] + 0.25f * stmp[1][my + 2][q];
    else    v = 0.25f * stmp[1][my][q]     + 0.75f * stmp[0][my + 1][q]
              + 0.75f * stmp[1][my + 1][q] + 0.25f * stmp[0][my + 2][q];
    float val = dm * v + bs;
    out[(bc * 64 + p) * 64 + q] = (val >= 0.f ? val : 0.2f * val) * 1.41421356237309515f;
  }
}

extern "C" void kernel_launch(void* const* d_in, const int* in_sizes, int n_in,
                              void* d_out, int out_size, void* d_ws, size_t ws_size,
                              hipStream_t stream) {
  const float* x      = (const float*)d_in[0];
  const float* style  = (const float*)d_in[1];
  const float* weight = (const float*)d_in[2];
  const float* mod_w  = (const float*)d_in[3];
  const float* mod_b  = (const float*)d_in[4];
  const float* bias   = (const float*)d_in[5];
  float* out = (float*)d_out;
  char* ws = (char*)d_ws;

  float* s     = (float*)(ws + OFF_S);
  float* wsq   = (float*)(ws + OFF_WSQ);
  float* demod = (float*)(ws + OFF_DEMOD);
  short* xp    = (short*)(ws + OFF_XP);
  short* wp    = (short*)(ws + OFF_WP);
  float* y1    = (float*)(ws + OFF_Y1);

  hipMemsetAsync(xp, 0, XP_BYTES, stream);
  k_style<<<128, 256, 0, stream>>>(style, mod_w, mod_b, s);
  k_wprep<<<1024, 256, 0, stream>>>(weight, wp, wsq);
  k_demod<<<128, 256, 0, stream>>>(wsq, s, demod);
  k_xprep<<<dim3(16, 8, 8), dim3(64, 4), 0, stream>>>(x, s, xp);
  k_gemm<<<dim3(69, 4, 4), 256, 0, stream>>>(xp, wp, y1);
  k_blur<<<4096, 256, 0, stream>>>(y1, demod, bias, out);
}